// Round 1
// baseline (489.763 us; speedup 1.0000x reference)
//
#include <hip/hip_runtime.h>

typedef unsigned short u16;
typedef __attribute__((ext_vector_type(8))) short short8;
typedef __attribute__((ext_vector_type(4))) float f32x4;
typedef __attribute__((ext_vector_type(4))) unsigned short u16x4;

#define DEV static __device__ __forceinline__

DEV u16 f2bf(float f){
    unsigned u = __float_as_uint(f);
    u += 0x7fffu + ((u >> 16) & 1u);   // round-to-nearest-even
    return (u16)(u >> 16);
}
DEV float bf2f(u16 h){ return __uint_as_float(((unsigned)h) << 16); }
DEV float sigm(float v){ return 1.f / (1.f + __expf(-v)); }

constexpr int Bn = 8, Sn = 2048, Dn = 1024;
constexpr int CH = 128, NC = Sn / CH;          // 16 chunks along S
constexpr size_t NTOK = (size_t)Bn * Sn;       // 16384 rows

// ---------------- weight convert + transpose: w[K,N] f32 -> wt[N,K] bf16 ----
__global__ __launch_bounds__(256) void k_wcvt(const float* __restrict__ w,
                                              u16* __restrict__ wt,
                                              int Kd, int Nd)
{
    __shared__ float tile[32][33];
    int nbn = Nd / 32;
    int bk = blockIdx.x / nbn, bn = blockIdx.x % nbn;
    int lx = threadIdx.x & 31, ly = threadIdx.x >> 5;   // 32 x 8
    #pragma unroll
    for (int i = 0; i < 32; i += 8)
        tile[ly + i][lx] = w[(size_t)(bk * 32 + ly + i) * Nd + bn * 32 + lx];
    __syncthreads();
    #pragma unroll
    for (int i = 0; i < 32; i += 8)
        wt[(size_t)(bn * 32 + ly + i) * Kd + bk * 32 + lx] = f2bf(tile[lx][ly + i]);
}

// ---------------- cumulative average (3-phase chunked scan) -----------------
__global__ __launch_bounds__(256) void k_psum(const float* __restrict__ x,
                                              float* __restrict__ part)
{
    int bx = blockIdx.x;
    int dblk = bx & 3; bx >>= 2;
    int c = bx & (NC - 1), b = bx >> 4;
    int d = dblk * 256 + threadIdx.x;
    const float* px = x + ((size_t)b * Sn + (size_t)c * CH) * Dn + d;
    float s = 0.f;
    #pragma unroll 4
    for (int i = 0; i < CH; i++) s += px[(size_t)i * Dn];
    part[((size_t)b * NC + c) * Dn + d] = s;
}

__global__ __launch_bounds__(256) void k_pscan(float* part)
{
    int g = blockIdx.x * 256 + threadIdx.x;   // 8192 columns
    int b = g >> 10, d = g & 1023;
    float run = 0.f;
    #pragma unroll
    for (int c = 0; c < NC; c++){
        size_t idx = ((size_t)b * NC + c) * Dn + d;
        float v = part[idx]; part[idx] = run; run += v;
    }
}

__global__ __launch_bounds__(256) void k_avg(const float* __restrict__ x,
                                             const float* __restrict__ part,
                                             float* __restrict__ avg)
{
    int bx = blockIdx.x;
    int dblk = bx & 3; bx >>= 2;
    int c = bx & (NC - 1), b = bx >> 4;
    int d = dblk * 256 + threadIdx.x;
    const float* px = x   + ((size_t)b * Sn + (size_t)c * CH) * Dn + d;
    float*       pa = avg + ((size_t)b * Sn + (size_t)c * CH) * Dn + d;
    float run = part[((size_t)b * NC + c) * Dn + d];
    for (int i = 0; i < CH; i++){
        run += px[(size_t)i * Dn];
        int s = c * CH + i;
        pa[(size_t)i * Dn] = run / (float)(s + 1);
    }
}

// ---------------- layernorm: avg f32 -> ln bf16 -----------------------------
__global__ __launch_bounds__(256) void k_ln(const float* __restrict__ avg,
                                            const float* __restrict__ g,
                                            const float* __restrict__ bta,
                                            u16* __restrict__ out)
{
    size_t row = blockIdx.x;
    int t = threadIdx.x;
    const float4* pr = (const float4*)(avg + row * Dn);
    float4 v = pr[t];
    float s = v.x + v.y + v.z + v.w;
    float q = v.x * v.x + v.y * v.y + v.z * v.z + v.w * v.w;
    #pragma unroll
    for (int o = 32; o > 0; o >>= 1){
        s += __shfl_down(s, o, 64);
        q += __shfl_down(q, o, 64);
    }
    __shared__ float rs[4], rq[4];
    __shared__ float smu, srstd;
    int wid = t >> 6, lane = t & 63;
    if (lane == 0){ rs[wid] = s; rq[wid] = q; }
    __syncthreads();
    if (t == 0){
        float S = rs[0] + rs[1] + rs[2] + rs[3];
        float Q = rq[0] + rq[1] + rq[2] + rq[3];
        float mu = S * (1.f / Dn);
        float var = Q * (1.f / Dn) - mu * mu;
        smu = mu; srstd = rsqrtf(var + 1e-6f);
    }
    __syncthreads();
    float mu = smu, rstd = srstd;
    int d0 = t * 4;
    float4 gg = ((const float4*)g)[t];
    float4 bb = ((const float4*)bta)[t];
    u16x4 o;
    o[0] = f2bf((v.x - mu) * rstd * gg.x + bb.x);
    o[1] = f2bf((v.y - mu) * rstd * gg.y + bb.y);
    o[2] = f2bf((v.z - mu) * rstd * gg.z + bb.z);
    o[3] = f2bf((v.w - mu) * rstd * gg.w + bb.w);
    *(u16x4*)(out + row * Dn + d0) = o;
}

// ---------------- x -> cat[:, 0:1024] bf16 ----------------------------------
__global__ __launch_bounds__(256) void k_xcat(const float* __restrict__ x,
                                              u16* __restrict__ cat)
{
    size_t i = (size_t)blockIdx.x * 256 + threadIdx.x;  // group of 4 elems
    size_t row = i >> 8; int d = (int)(i & 255) * 4;
    float4 v = *(const float4*)(x + row * Dn + d);
    u16x4 o = { f2bf(v.x), f2bf(v.y), f2bf(v.z), f2bf(v.w) };
    *(u16x4*)(cat + row * 2 * Dn + d) = o;
}

// ---------------- bf16 MFMA GEMM: C = A[M,K] x Bt[N,K]^T + bias -------------
// EPI 1: ob = bf16(relu(v))                       (inter)
// EPI 2: v += resid; of = v; ob[2N stride,+N] = bf16(v)   (avg_out + cat)
// EPI 3: ob = bf16(v)                             (gates)
template<int EPI>
__global__ __launch_bounds__(256)
void k_gemm(const u16* __restrict__ A, const u16* __restrict__ Bt,
            const float* __restrict__ bias,
            float* __restrict__ of, u16* __restrict__ ob,
            const float* __restrict__ resid,
            int M, int N, int K)
{
    constexpr int BM = 128, BN = 128, BK = 32, LDT = BK + 8;
    __shared__ u16 sa[BM * LDT];
    __shared__ u16 sb[BN * LDT];
    int nbn = N / BN;
    int bn = blockIdx.x % nbn, bm = blockIdx.x / nbn;
    int m0 = bm * BM, n0 = bn * BN;
    int tid = threadIdx.x;
    int wid = tid >> 6, lane = tid & 63;
    int wm = wid >> 1, wn = wid & 1;
    int fr = lane & 15, kg = (lane >> 4) * 8;

    f32x4 acc[4][4] = {};

    for (int k0 = 0; k0 < K; k0 += BK){
        __syncthreads();
        #pragma unroll
        for (int i = 0; i < 2; i++){
            int c = i * 256 + tid;          // 0..511
            int row = c >> 2, col = (c & 3) * 8;
            *(int4*)(&sa[row * LDT + col]) =
                *(const int4*)(&A[(size_t)(m0 + row) * K + k0 + col]);
            *(int4*)(&sb[row * LDT + col]) =
                *(const int4*)(&Bt[(size_t)(n0 + row) * K + k0 + col]);
        }
        __syncthreads();
        short8 af[4], bfr[4];
        #pragma unroll
        for (int mi = 0; mi < 4; mi++)
            af[mi] = *(const short8*)(&sa[(wm * 64 + mi * 16 + fr) * LDT + kg]);
        #pragma unroll
        for (int ni = 0; ni < 4; ni++)
            bfr[ni] = *(const short8*)(&sb[(wn * 64 + ni * 16 + fr) * LDT + kg]);
        #pragma unroll
        for (int mi = 0; mi < 4; mi++)
            #pragma unroll
            for (int ni = 0; ni < 4; ni++)
                acc[mi][ni] = __builtin_amdgcn_mfma_f32_16x16x32_bf16(
                    af[mi], bfr[ni], acc[mi][ni], 0, 0, 0);
    }

    int col = lane & 15, rb = (lane >> 4) * 4;
    #pragma unroll
    for (int mi = 0; mi < 4; mi++){
        #pragma unroll
        for (int ni = 0; ni < 4; ni++){
            int gn = n0 + wn * 64 + ni * 16 + col;
            float bv = bias[gn];
            #pragma unroll
            for (int r = 0; r < 4; r++){
                int gm = m0 + wm * 64 + mi * 16 + rb + r;
                float v = acc[mi][ni][r] + bv;
                if constexpr (EPI == 1){
                    ob[(size_t)gm * N + gn] = f2bf(fmaxf(v, 0.f));
                } else if constexpr (EPI == 2){
                    v += resid[(size_t)gm * N + gn];
                    of[(size_t)gm * N + gn] = v;
                    ob[(size_t)gm * 2 * N + N + gn] = f2bf(v);
                } else {
                    ob[(size_t)gm * N + gn] = f2bf(v);
                }
            }
        }
    }
}

// ---------------- final gating ----------------------------------------------
__global__ __launch_bounds__(256) void k_gate(const u16* __restrict__ gates,
                                              const float* __restrict__ x,
                                              const float* __restrict__ aout,
                                              float* __restrict__ out)
{
    size_t i = (size_t)blockIdx.x * 256 + threadIdx.x;  // group of 4
    size_t row = i >> 8; int d = (int)(i & 255) * 4;
    u16x4 g1 = *(const u16x4*)(gates + row * 2048 + d);
    u16x4 g2 = *(const u16x4*)(gates + row * 2048 + 1024 + d);
    float4 xv = *(const float4*)(x + row * Dn + d);
    float4 av = *(const float4*)(aout + row * Dn + d);
    float4 o;
    o.x = sigm(bf2f(g1[0])) * xv.x + sigm(bf2f(g2[0])) * av.x;
    o.y = sigm(bf2f(g1[1])) * xv.y + sigm(bf2f(g2[1])) * av.y;
    o.z = sigm(bf2f(g1[2])) * xv.z + sigm(bf2f(g2[2])) * av.z;
    o.w = sigm(bf2f(g1[3])) * xv.w + sigm(bf2f(g2[3])) * av.w;
    *(float4*)(out + row * Dn + d) = o;
}

// ---------------- launch -----------------------------------------------------
extern "C" void kernel_launch(void* const* d_in, const int* in_sizes, int n_in,
                              void* d_out, int out_size, void* d_ws, size_t ws_size,
                              hipStream_t stream)
{
    const float* x   = (const float*)d_in[0];
    const float* w1  = (const float*)d_in[1];
    const float* b1  = (const float*)d_in[2];
    const float* w2  = (const float*)d_in[3];
    const float* b2  = (const float*)d_in[4];
    const float* lng = (const float*)d_in[5];
    const float* lnb = (const float*)d_in[6];
    const float* wg  = (const float*)d_in[7];
    const float* bg  = (const float*)d_in[8];

    float* gated   = (float*)d_out;                    // [16384,1024]
    float* avg_out = (float*)d_out + NTOK * Dn;        // [16384,1024]

    char* ws = (char*)d_ws;
    u16*   w1t   = (u16*)  (ws + (0ull   << 20));      // 2 MB
    u16*   w2t   = (u16*)  (ws + (2ull   << 20));      // 2 MB
    u16*   wgt   = (u16*)  (ws + (4ull   << 20));      // 8 MB
    float* part  = (float*)(ws + (12ull  << 20));      // 0.5 MB
    float* avg   = (float*)(ws + (16ull  << 20));      // 64 MB
    u16*   ln    = (u16*)  (ws + (80ull  << 20));      // 32 MB
    u16*   inter = (u16*)  (ws + (112ull << 20));      // 32 MB
    u16*   cat   = (u16*)  (ws + (144ull << 20));      // 64 MB  -> total 208 MB
    u16*   gates = ln;  // reuse [80,144) MB: ln+inter dead before gating GEMM

    // weights -> bf16 transposed [N,K]
    k_wcvt<<<dim3(32 * 32), 256, 0, stream>>>(w1, w1t, Dn, Dn);
    k_wcvt<<<dim3(32 * 32), 256, 0, stream>>>(w2, w2t, Dn, Dn);
    k_wcvt<<<dim3(64 * 64), 256, 0, stream>>>(wg, wgt, 2 * Dn, 2 * Dn);

    // cumulative average
    k_psum <<<dim3(Bn * NC * 4), 256, 0, stream>>>(x, part);
    k_pscan<<<dim3(Bn * Dn / 256), 256, 0, stream>>>(part);
    k_avg  <<<dim3(Bn * NC * 4), 256, 0, stream>>>(x, part, avg);

    // LN and x->cat conversion
    k_ln  <<<dim3((int)NTOK), 256, 0, stream>>>(avg, lng, lnb, ln);
    k_xcat<<<dim3((int)(NTOK * Dn / 1024)), 256, 0, stream>>>(x, cat);

    // FFN GEMMs
    k_gemm<1><<<dim3((int)(NTOK / 128) * (Dn / 128)), 256, 0, stream>>>(
        ln, w1t, b1, nullptr, inter, nullptr, (int)NTOK, Dn, Dn);
    k_gemm<2><<<dim3((int)(NTOK / 128) * (Dn / 128)), 256, 0, stream>>>(
        inter, w2t, b2, avg_out, cat, avg, (int)NTOK, Dn, Dn);

    // gating GEMM + combine
    k_gemm<3><<<dim3((int)(NTOK / 128) * (2 * Dn / 128)), 256, 0, stream>>>(
        cat, wgt, bg, nullptr, gates, nullptr, (int)NTOK, 2 * Dn, 2 * Dn);
    k_gate<<<dim3((int)(NTOK * Dn / 1024)), 256, 0, stream>>>(gates, x, avg_out, gated);
}

// Round 2
// 381.275 us; speedup vs baseline: 1.2845x; 1.2845x over previous
//
#include <hip/hip_runtime.h>

typedef unsigned short u16;
typedef __attribute__((ext_vector_type(8))) short short8;
typedef __attribute__((ext_vector_type(4))) float f32x4;
typedef __attribute__((ext_vector_type(4))) unsigned short u16x4;

#define DEV static __device__ __forceinline__

DEV u16 f2bf(float f){
    unsigned u = __float_as_uint(f);
    u += 0x7fffu + ((u >> 16) & 1u);   // round-to-nearest-even
    return (u16)(u >> 16);
}
DEV float bf2f(u16 h){ return __uint_as_float(((unsigned)h) << 16); }
DEV float sigm(float v){ return 1.f / (1.f + __expf(-v)); }

DEV f32x4 MF(short8 a, short8 b, f32x4 c){
    return __builtin_amdgcn_mfma_f32_16x16x32_bf16(a, b, c, 0, 0, 0);
}
DEV void gload16(const void* g, u16* l){
    __builtin_amdgcn_global_load_lds(
        (const __attribute__((address_space(1))) void*)g,
        (__attribute__((address_space(3))) void*)l, 16, 0, 0);
}

#define SBAR()  asm volatile("s_barrier" ::: "memory")
#define WVM0()  asm volatile("s_waitcnt vmcnt(0)" ::: "memory")
#define WLG0()  asm volatile("s_waitcnt lgkmcnt(0)" ::: "memory")

constexpr int Bn = 8, Sn = 2048, Dn = 1024;
constexpr int CH = 128, NC = Sn / CH;          // 16 chunks along S
constexpr size_t NTOK = (size_t)Bn * Sn;       // 16384 rows

// ---------------- weight convert + transpose: w[K,N] f32 -> wt[N,K] bf16 ----
__global__ __launch_bounds__(256) void k_wcvt(const float* __restrict__ w,
                                              u16* __restrict__ wt,
                                              int Kd, int Nd)
{
    __shared__ float tile[32][33];
    int nbn = Nd / 32;
    int bk = blockIdx.x / nbn, bn = blockIdx.x % nbn;
    int lx = threadIdx.x & 31, ly = threadIdx.x >> 5;   // 32 x 8
    #pragma unroll
    for (int i = 0; i < 32; i += 8)
        tile[ly + i][lx] = w[(size_t)(bk * 32 + ly + i) * Nd + bn * 32 + lx];
    __syncthreads();
    #pragma unroll
    for (int i = 0; i < 32; i += 8)
        wt[(size_t)(bn * 32 + ly + i) * Kd + bk * 32 + lx] = f2bf(tile[lx][ly + i]);
}

// ---------------- cumulative average (3-phase chunked scan) -----------------
__global__ __launch_bounds__(256) void k_psum(const float* __restrict__ x,
                                              float* __restrict__ part)
{
    int bx = blockIdx.x;
    int dblk = bx & 3; bx >>= 2;
    int c = bx & (NC - 1), b = bx >> 4;
    int d = dblk * 256 + threadIdx.x;
    const float* px = x + ((size_t)b * Sn + (size_t)c * CH) * Dn + d;
    float s = 0.f;
    #pragma unroll 4
    for (int i = 0; i < CH; i++) s += px[(size_t)i * Dn];
    part[((size_t)b * NC + c) * Dn + d] = s;
}

__global__ __launch_bounds__(256) void k_pscan(float* part)
{
    int g = blockIdx.x * 256 + threadIdx.x;   // 8192 columns
    int b = g >> 10, d = g & 1023;
    float run = 0.f;
    #pragma unroll
    for (int c = 0; c < NC; c++){
        size_t idx = ((size_t)b * NC + c) * Dn + d;
        float v = part[idx]; part[idx] = run; run += v;
    }
}

// avg + fused x->cat[:,0:1024] bf16 write
__global__ __launch_bounds__(256) void k_avg(const float* __restrict__ x,
                                             const float* __restrict__ part,
                                             float* __restrict__ avg,
                                             u16* __restrict__ cat)
{
    int bx = blockIdx.x;
    int dblk = bx & 3; bx >>= 2;
    int c = bx & (NC - 1), b = bx >> 4;
    int d = dblk * 256 + threadIdx.x;
    const float* px = x   + ((size_t)b * Sn + (size_t)c * CH) * Dn + d;
    float*       pa = avg + ((size_t)b * Sn + (size_t)c * CH) * Dn + d;
    u16*         pc = cat + ((size_t)b * Sn + (size_t)c * CH) * 2048 + d;
    float run = part[((size_t)b * NC + c) * Dn + d];
    for (int i = 0; i < CH; i++){
        float v = px[(size_t)i * Dn];
        run += v;
        int s = c * CH + i;
        pa[(size_t)i * Dn] = run / (float)(s + 1);
        pc[(size_t)i * 2048] = f2bf(v);
    }
}

// ---------------- layernorm: avg f32 -> ln bf16 -----------------------------
__global__ __launch_bounds__(256) void k_ln(const float* __restrict__ avg,
                                            const float* __restrict__ g,
                                            const float* __restrict__ bta,
                                            u16* __restrict__ out)
{
    size_t row = blockIdx.x;
    int t = threadIdx.x;
    const float4* pr = (const float4*)(avg + row * Dn);
    float4 v = pr[t];
    float s = v.x + v.y + v.z + v.w;
    float q = v.x * v.x + v.y * v.y + v.z * v.z + v.w * v.w;
    #pragma unroll
    for (int o = 32; o > 0; o >>= 1){
        s += __shfl_down(s, o, 64);
        q += __shfl_down(q, o, 64);
    }
    __shared__ float rs[4], rq[4];
    __shared__ float smu, srstd;
    int wid = t >> 6, lane = t & 63;
    if (lane == 0){ rs[wid] = s; rq[wid] = q; }
    __syncthreads();
    if (t == 0){
        float S = rs[0] + rs[1] + rs[2] + rs[3];
        float Q = rq[0] + rq[1] + rq[2] + rq[3];
        float mu = S * (1.f / Dn);
        float var = Q * (1.f / Dn) - mu * mu;
        smu = mu; srstd = rsqrtf(var + 1e-6f);
    }
    __syncthreads();
    float mu = smu, rstd = srstd;
    int d0 = t * 4;
    float4 gg = ((const float4*)g)[t];
    float4 bb = ((const float4*)bta)[t];
    u16x4 o;
    o[0] = f2bf((v.x - mu) * rstd * gg.x + bb.x);
    o[1] = f2bf((v.y - mu) * rstd * gg.y + bb.y);
    o[2] = f2bf((v.z - mu) * rstd * gg.z + bb.z);
    o[3] = f2bf((v.w - mu) * rstd * gg.w + bb.w);
    *(u16x4*)(out + row * Dn + d0) = o;
}

// ---------------- 256x256x64 4-phase MFMA GEMM: C = A[M,K] x Bt[N,K]^T + bias
// EPI 1: ob = bf16(relu(v))                       (inter)
// EPI 2: v += resid; of = v; ob[2N stride,+N] = bf16(v)   (avg_out + cat)
// EPI 3: ob = bf16(v)                             (gates)
template<int EPI>
__global__ __launch_bounds__(512, 2)
void k_gemm(const u16* __restrict__ A, const u16* __restrict__ Bt,
            const float* __restrict__ bias,
            float* __restrict__ of, u16* __restrict__ ob,
            const float* __restrict__ resid,
            int M, int N, int K)
{
    __shared__ u16 sA[2][16384];   // [buf][256 rows][64 cols], 32 KB each
    __shared__ u16 sB[2][16384];

    // XCD-aware bijective swizzle (nwg % 8 == 0 for all our shapes)
    int nbn = N >> 8;
    int nwg = (M >> 8) * nbn;
    int bid = blockIdx.x;
    int swz = (bid & 7) * (nwg >> 3) + (bid >> 3);
    int bm = swz / nbn, bn = swz - bm * nbn;
    int m0 = bm << 8, n0 = bn << 8;

    int tid  = threadIdx.x;
    int wid  = tid >> 6, lane = tid & 63;
    int wm   = wid >> 2, wn = wid & 3;      // 2 x 4 wave grid, 128x64 out/wave
    int fr   = lane & 15, q = lane >> 4;

    // staging: wave w stages rows w*32..w*32+31 of both tiles; 4 insts each,
    // 1 KB (8 rows x 128 B) per inst. Source pre-swizzled (rule #21): LDS is
    // written linearly, global col byte = phys ^ ((row&7)<<4).
    int ric = lane >> 3;                       // row in 8-row chunk
    int cb  = ((lane & 7) << 4) ^ (ric << 4);  // swizzled source col byte
    const char* gA = (const char*)A  + (((size_t)(m0 + wid*32 + ric) * K) << 1) + cb;
    const char* gB = (const char*)Bt + (((size_t)(n0 + wid*32 + ric) * K) << 1) + cb;
    size_t str8 = (size_t)K << 4;              // 8 rows stride in bytes
    int sRow = wid * 32 * 64;                  // stage dst base (elements)

    // fragment reads: logical col e -> phys e ^ ((row&7)*8); row&7 == fr&7
    int xorE = (lane & 7) << 3;
    int cbE0 = (q << 3) ^ xorE;                // k-step 0
    int cbE1 = cbE0 ^ 32;                      // k-step 1
    int aB0 = (wm * 128 + fr) * 64;
    int bB0 = (wn * 64  + fr) * 64;

    f32x4 acc[8][4] = {};
    int NT = K >> 6;

    #pragma unroll
    for (int i = 0; i < 4; i++){
        gload16(gA + (size_t)i * str8, &sA[0][sRow + i * 512]);
        gload16(gB + (size_t)i * str8, &sB[0][sRow + i * 512]);
    }

    for (int kt = 0; kt < NT; kt++){
        int cur = kt & 1, nxt = cur ^ 1;
        bool pre = (kt + 1) < NT;
        const char* pA = gA + (size_t)(kt + 1) * 128;
        const char* pB = gB + (size_t)(kt + 1) * 128;

        WVM0(); SBAR();   // all waves' stages for tile kt landed

        short8 af[4][2], b0[2][2], b1[2][2];
        // ---- P0: read A-half0 + B-half0, stage 2, MFMA quad(0,0)
        #pragma unroll
        for (int mi = 0; mi < 4; mi++){
            af[mi][0] = *(const short8*)&sA[cur][aB0 + mi * 1024 + cbE0];
            af[mi][1] = *(const short8*)&sA[cur][aB0 + mi * 1024 + cbE1];
        }
        #pragma unroll
        for (int ni = 0; ni < 2; ni++){
            b0[ni][0] = *(const short8*)&sB[cur][bB0 + ni * 1024 + cbE0];
            b0[ni][1] = *(const short8*)&sB[cur][bB0 + ni * 1024 + cbE1];
        }
        if (pre){
            gload16(pA,        &sA[nxt][sRow]);
            gload16(pA + str8, &sA[nxt][sRow + 512]);
        }
        SBAR(); WLG0();
        __builtin_amdgcn_sched_barrier(0);
        __builtin_amdgcn_s_setprio(1);
        #pragma unroll
        for (int mi = 0; mi < 4; mi++)
            #pragma unroll
            for (int ni = 0; ni < 2; ni++){
                acc[mi][ni] = MF(af[mi][0], b0[ni][0], acc[mi][ni]);
                acc[mi][ni] = MF(af[mi][1], b0[ni][1], acc[mi][ni]);
            }
        __builtin_amdgcn_s_setprio(0);
        SBAR();
        // ---- P1: read B-half1, stage 2, MFMA quad(0,1)
        #pragma unroll
        for (int ni = 0; ni < 2; ni++){
            b1[ni][0] = *(const short8*)&sB[cur][bB0 + (ni + 2) * 1024 + cbE0];
            b1[ni][1] = *(const short8*)&sB[cur][bB0 + (ni + 2) * 1024 + cbE1];
        }
        if (pre){
            gload16(pA + 2 * str8, &sA[nxt][sRow + 1024]);
            gload16(pA + 3 * str8, &sA[nxt][sRow + 1536]);
        }
        SBAR(); WLG0();
        __builtin_amdgcn_sched_barrier(0);
        __builtin_amdgcn_s_setprio(1);
        #pragma unroll
        for (int mi = 0; mi < 4; mi++)
            #pragma unroll
            for (int ni = 0; ni < 2; ni++){
                acc[mi][ni + 2] = MF(af[mi][0], b1[ni][0], acc[mi][ni + 2]);
                acc[mi][ni + 2] = MF(af[mi][1], b1[ni][1], acc[mi][ni + 2]);
            }
        __builtin_amdgcn_s_setprio(0);
        SBAR();
        // ---- P2: read A-half1 (overwrite af), stage 2, MFMA quad(1,1)
        #pragma unroll
        for (int mi = 0; mi < 4; mi++){
            af[mi][0] = *(const short8*)&sA[cur][aB0 + (mi + 4) * 1024 + cbE0];
            af[mi][1] = *(const short8*)&sA[cur][aB0 + (mi + 4) * 1024 + cbE1];
        }
        if (pre){
            gload16(pB,        &sB[nxt][sRow]);
            gload16(pB + str8, &sB[nxt][sRow + 512]);
        }
        SBAR(); WLG0();
        __builtin_amdgcn_sched_barrier(0);
        __builtin_amdgcn_s_setprio(1);
        #pragma unroll
        for (int mi = 0; mi < 4; mi++)
            #pragma unroll
            for (int ni = 0; ni < 2; ni++){
                acc[mi + 4][ni + 2] = MF(af[mi][0], b1[ni][0], acc[mi + 4][ni + 2]);
                acc[mi + 4][ni + 2] = MF(af[mi][1], b1[ni][1], acc[mi + 4][ni + 2]);
            }
        __builtin_amdgcn_s_setprio(0);
        SBAR();
        // ---- P3: stage 2, MFMA quad(1,0) (reuses b0)
        if (pre){
            gload16(pB + 2 * str8, &sB[nxt][sRow + 1024]);
            gload16(pB + 3 * str8, &sB[nxt][sRow + 1536]);
        }
        SBAR();
        __builtin_amdgcn_s_setprio(1);
        #pragma unroll
        for (int mi = 0; mi < 4; mi++)
            #pragma unroll
            for (int ni = 0; ni < 2; ni++){
                acc[mi + 4][ni] = MF(af[mi][0], b0[ni][0], acc[mi + 4][ni]);
                acc[mi + 4][ni] = MF(af[mi][1], b0[ni][1], acc[mi + 4][ni]);
            }
        __builtin_amdgcn_s_setprio(0);
        SBAR();
    }

    // ---- epilogue: C/D layout col = lane&15, row = (lane>>4)*4 + r
    int col = lane & 15, rb = q * 4;
    #pragma unroll
    for (int mi = 0; mi < 8; mi++){
        #pragma unroll
        for (int ni = 0; ni < 4; ni++){
            int gn = n0 + wn * 64 + ni * 16 + col;
            float bv = bias[gn];
            #pragma unroll
            for (int r = 0; r < 4; r++){
                int gm = m0 + wm * 128 + mi * 16 + rb + r;
                float v = acc[mi][ni][r] + bv;
                if constexpr (EPI == 1){
                    ob[(size_t)gm * N + gn] = f2bf(fmaxf(v, 0.f));
                } else if constexpr (EPI == 2){
                    v += resid[(size_t)gm * N + gn];
                    of[(size_t)gm * N + gn] = v;
                    ob[(size_t)gm * 2 * N + N + gn] = f2bf(v);
                } else {
                    ob[(size_t)gm * N + gn] = f2bf(v);
                }
            }
        }
    }
}

// ---------------- final gating ----------------------------------------------
__global__ __launch_bounds__(256) void k_gate(const u16* __restrict__ gates,
                                              const float* __restrict__ x,
                                              const float* __restrict__ aout,
                                              float* __restrict__ out)
{
    size_t i = (size_t)blockIdx.x * 256 + threadIdx.x;  // group of 4
    size_t row = i >> 8; int d = (int)(i & 255) * 4;
    u16x4 g1 = *(const u16x4*)(gates + row * 2048 + d);
    u16x4 g2 = *(const u16x4*)(gates + row * 2048 + 1024 + d);
    float4 xv = *(const float4*)(x + row * Dn + d);
    float4 av = *(const float4*)(aout + row * Dn + d);
    float4 o;
    o.x = sigm(bf2f(g1[0])) * xv.x + sigm(bf2f(g2[0])) * av.x;
    o.y = sigm(bf2f(g1[1])) * xv.y + sigm(bf2f(g2[1])) * av.y;
    o.z = sigm(bf2f(g1[2])) * xv.z + sigm(bf2f(g2[2])) * av.z;
    o.w = sigm(bf2f(g1[3])) * xv.w + sigm(bf2f(g2[3])) * av.w;
    *(float4*)(out + row * Dn + d) = o;
}

// ---------------- launch -----------------------------------------------------
extern "C" void kernel_launch(void* const* d_in, const int* in_sizes, int n_in,
                              void* d_out, int out_size, void* d_ws, size_t ws_size,
                              hipStream_t stream)
{
    const float* x   = (const float*)d_in[0];
    const float* w1  = (const float*)d_in[1];
    const float* b1  = (const float*)d_in[2];
    const float* w2  = (const float*)d_in[3];
    const float* b2  = (const float*)d_in[4];
    const float* lng = (const float*)d_in[5];
    const float* lnb = (const float*)d_in[6];
    const float* wg  = (const float*)d_in[7];
    const float* bg  = (const float*)d_in[8];

    float* gated   = (float*)d_out;                    // [16384,1024]
    float* avg_out = (float*)d_out + NTOK * Dn;        // [16384,1024]

    char* ws = (char*)d_ws;
    u16*   w1t   = (u16*)  (ws + (0ull   << 20));      // 2 MB
    u16*   w2t   = (u16*)  (ws + (2ull   << 20));      // 2 MB
    u16*   wgt   = (u16*)  (ws + (4ull   << 20));      // 8 MB
    float* part  = (float*)(ws + (12ull  << 20));      // 0.5 MB
    float* avg   = (float*)(ws + (16ull  << 20));      // 64 MB
    u16*   ln    = (u16*)  (ws + (80ull  << 20));      // 32 MB
    u16*   inter = (u16*)  (ws + (112ull << 20));      // 32 MB
    u16*   cat   = (u16*)  (ws + (144ull << 20));      // 64 MB  -> total 208 MB
    u16*   gates = ln;  // reuse [80,144): ln+inter dead before gating GEMM

    // weights -> bf16 transposed [N,K]
    k_wcvt<<<dim3(32 * 32), 256, 0, stream>>>(w1, w1t, Dn, Dn);
    k_wcvt<<<dim3(32 * 32), 256, 0, stream>>>(w2, w2t, Dn, Dn);
    k_wcvt<<<dim3(64 * 64), 256, 0, stream>>>(wg, wgt, 2 * Dn, 2 * Dn);

    // cumulative average (+ fused x->cat bf16)
    k_psum <<<dim3(Bn * NC * 4), 256, 0, stream>>>(x, part);
    k_pscan<<<dim3(Bn * Dn / 256), 256, 0, stream>>>(part);
    k_avg  <<<dim3(Bn * NC * 4), 256, 0, stream>>>(x, part, avg, cat);

    // LN
    k_ln<<<dim3((int)NTOK), 256, 0, stream>>>(avg, lng, lnb, ln);

    // FFN GEMMs (256x256 tiles, 512 threads)
    k_gemm<1><<<dim3((int)(NTOK / 256) * (Dn / 256)), 512, 0, stream>>>(
        ln, w1t, b1, nullptr, inter, nullptr, (int)NTOK, Dn, Dn);
    k_gemm<2><<<dim3((int)(NTOK / 256) * (Dn / 256)), 512, 0, stream>>>(
        inter, w2t, b2, avg_out, cat, avg, (int)NTOK, Dn, Dn);

    // gating GEMM + combine
    k_gemm<3><<<dim3((int)(NTOK / 256) * (2 * Dn / 256)), 512, 0, stream>>>(
        cat, wgt, bg, nullptr, gates, nullptr, (int)NTOK, 2 * Dn, 2 * Dn);
    k_gate<<<dim3((int)(NTOK * Dn / 1024)), 256, 0, stream>>>(gates, x, avg_out, gated);
}

// Round 3
// 376.700 us; speedup vs baseline: 1.3001x; 1.0121x over previous
//
#include <hip/hip_runtime.h>

typedef unsigned short u16;
typedef __attribute__((ext_vector_type(8))) short short8;
typedef __attribute__((ext_vector_type(4))) float f32x4;
typedef __attribute__((ext_vector_type(4))) unsigned short u16x4;

#define DEV static __device__ __forceinline__

DEV u16 f2bf(float f){
    unsigned u = __float_as_uint(f);
    u += 0x7fffu + ((u >> 16) & 1u);   // round-to-nearest-even
    return (u16)(u >> 16);
}
DEV float bf2f(u16 h){ return __uint_as_float(((unsigned)h) << 16); }
DEV float sigm(float v){ return 1.f / (1.f + __expf(-v)); }

DEV f32x4 MF(short8 a, short8 b, f32x4 c){
    return __builtin_amdgcn_mfma_f32_16x16x32_bf16(a, b, c, 0, 0, 0);
}
DEV void gload16(const void* g, u16* l){
    __builtin_amdgcn_global_load_lds(
        (const __attribute__((address_space(1))) void*)g,
        (__attribute__((address_space(3))) void*)l, 16, 0, 0);
}

#define SBAR()   asm volatile("s_barrier" ::: "memory")
#define WVM0()   asm volatile("s_waitcnt vmcnt(0)" ::: "memory")
#define WVM8()   asm volatile("s_waitcnt vmcnt(8)" ::: "memory")
#define WLG0()   asm volatile("s_waitcnt lgkmcnt(0)" ::: "memory")

constexpr int Bn = 8, Sn = 2048, Dn = 1024;
constexpr int CH = 128, NC = Sn / CH;          // 16 chunks along S
constexpr size_t NTOK = (size_t)Bn * Sn;       // 16384 rows

// ---------------- weight convert + transpose: w[K,N] f32 -> wt[N,K] bf16 ----
__global__ __launch_bounds__(256) void k_wcvt(const float* __restrict__ w,
                                              u16* __restrict__ wt,
                                              int Kd, int Nd)
{
    __shared__ float tile[32][33];
    int nbn = Nd / 32;
    int bk = blockIdx.x / nbn, bn = blockIdx.x % nbn;
    int lx = threadIdx.x & 31, ly = threadIdx.x >> 5;   // 32 x 8
    #pragma unroll
    for (int i = 0; i < 32; i += 8)
        tile[ly + i][lx] = w[(size_t)(bk * 32 + ly + i) * Nd + bn * 32 + lx];
    __syncthreads();
    #pragma unroll
    for (int i = 0; i < 32; i += 8)
        wt[(size_t)(bn * 32 + ly + i) * Kd + bk * 32 + lx] = f2bf(tile[lx][ly + i]);
}

// ---------------- cumulative average (3-phase chunked scan) -----------------
__global__ __launch_bounds__(256) void k_psum(const float* __restrict__ x,
                                              float* __restrict__ part)
{
    int bx = blockIdx.x;
    int dblk = bx & 3; bx >>= 2;
    int c = bx & (NC - 1), b = bx >> 4;
    int d = dblk * 256 + threadIdx.x;
    const float* px = x + ((size_t)b * Sn + (size_t)c * CH) * Dn + d;
    float s = 0.f;
    #pragma unroll 4
    for (int i = 0; i < CH; i++) s += px[(size_t)i * Dn];
    part[((size_t)b * NC + c) * Dn + d] = s;
}

__global__ __launch_bounds__(256) void k_pscan(float* part)
{
    int g = blockIdx.x * 256 + threadIdx.x;   // 8192 columns
    int b = g >> 10, d = g & 1023;
    float run = 0.f;
    #pragma unroll
    for (int c = 0; c < NC; c++){
        size_t idx = ((size_t)b * NC + c) * Dn + d;
        float v = part[idx]; part[idx] = run; run += v;
    }
}

// avg + fused x->cat[:,0:1024] bf16 write
__global__ __launch_bounds__(256) void k_avg(const float* __restrict__ x,
                                             const float* __restrict__ part,
                                             float* __restrict__ avg,
                                             u16* __restrict__ cat)
{
    int bx = blockIdx.x;
    int dblk = bx & 3; bx >>= 2;
    int c = bx & (NC - 1), b = bx >> 4;
    int d = dblk * 256 + threadIdx.x;
    const float* px = x   + ((size_t)b * Sn + (size_t)c * CH) * Dn + d;
    float*       pa = avg + ((size_t)b * Sn + (size_t)c * CH) * Dn + d;
    u16*         pc = cat + ((size_t)b * Sn + (size_t)c * CH) * 2048 + d;
    float run = part[((size_t)b * NC + c) * Dn + d];
    for (int i = 0; i < CH; i++){
        float v = px[(size_t)i * Dn];
        run += v;
        int s = c * CH + i;
        pa[(size_t)i * Dn] = run / (float)(s + 1);
        pc[(size_t)i * 2048] = f2bf(v);
    }
}

// ---------------- layernorm: avg f32 -> ln bf16 -----------------------------
__global__ __launch_bounds__(256) void k_ln(const float* __restrict__ avg,
                                            const float* __restrict__ g,
                                            const float* __restrict__ bta,
                                            u16* __restrict__ out)
{
    size_t row = blockIdx.x;
    int t = threadIdx.x;
    const float4* pr = (const float4*)(avg + row * Dn);
    float4 v = pr[t];
    float s = v.x + v.y + v.z + v.w;
    float q = v.x * v.x + v.y * v.y + v.z * v.z + v.w * v.w;
    #pragma unroll
    for (int o = 32; o > 0; o >>= 1){
        s += __shfl_down(s, o, 64);
        q += __shfl_down(q, o, 64);
    }
    __shared__ float rs[4], rq[4];
    __shared__ float smu, srstd;
    int wid = t >> 6, lane = t & 63;
    if (lane == 0){ rs[wid] = s; rq[wid] = q; }
    __syncthreads();
    if (t == 0){
        float S = rs[0] + rs[1] + rs[2] + rs[3];
        float Q = rq[0] + rq[1] + rq[2] + rq[3];
        float mu = S * (1.f / Dn);
        float var = Q * (1.f / Dn) - mu * mu;
        smu = mu; srstd = rsqrtf(var + 1e-6f);
    }
    __syncthreads();
    float mu = smu, rstd = srstd;
    int d0 = t * 4;
    float4 gg = ((const float4*)g)[t];
    float4 bb = ((const float4*)bta)[t];
    u16x4 o;
    o[0] = f2bf((v.x - mu) * rstd * gg.x + bb.x);
    o[1] = f2bf((v.y - mu) * rstd * gg.y + bb.y);
    o[2] = f2bf((v.z - mu) * rstd * gg.z + bb.z);
    o[3] = f2bf((v.w - mu) * rstd * gg.w + bb.w);
    *(u16x4*)(out + row * Dn + d0) = o;
}

// ---------------- 256x256x64 MFMA GEMM, depth-1 counted-vmcnt pipeline ------
// C = A[M,K] x Bt[N,K]^T + bias
// EPI 1: ob = bf16(relu(v))                                  (inter)
// EPI 2: v += resid; of = v; ob[2N stride,+N] = bf16(v)      (avg_out + cat)
// EPI 3: paired-panel gating: B tile rows = [n0,n0+128)u[n0+1024,n0+1128),
//        of = sig(in)*xg + sig(fg)*ag  (gated), via LDS exchange
template<int EPI>
__global__ __launch_bounds__(512, 2)
void k_gemm(const u16* __restrict__ A, const u16* __restrict__ Bt,
            const float* __restrict__ bias,
            float* __restrict__ of, u16* __restrict__ ob,
            const float* __restrict__ resid,
            const float* __restrict__ xg, const float* __restrict__ ag,
            int M, int N, int K)
{
    __shared__ u16 smem[2][2][16384];   // [buf][A|B][256 rows][64 cols] 128 KB

    // XCD-aware bijective swizzle (nwg % 8 == 0 for all our shapes)
    int nbn = (EPI == 3) ? 8 : (N >> 8);
    int nwg = (M >> 8) * nbn;
    int bid = blockIdx.x;
    int swz = (bid & 7) * (nwg >> 3) + (bid >> 3);
    int bm = swz / nbn, bn = swz - bm * nbn;
    int m0 = bm << 8;
    int n0 = (EPI == 3) ? (bn << 7) : (bn << 8);

    int tid  = threadIdx.x;
    int wid  = tid >> 6, lane = tid & 63;
    int wm   = wid >> 2, wn = wid & 3;      // 2 x 4 wave grid, 128x64 out/wave
    int fr   = lane & 15, q = lane >> 4;

    // staging: wave w stages rows w*32..w*32+31 of both tiles; 4 insts each,
    // 1 KB (8 rows x 128 B) per inst. Source pre-swizzled (rule #21): LDS is
    // written linearly, global col byte = phys ^ ((row&7)<<4).
    int ric = lane >> 3;                       // row in 8-row chunk
    int cb  = ((lane & 7) << 4) ^ (ric << 4);  // swizzled source col byte
    int brow = n0 + wid * 32 + ric;
    if (EPI == 3 && wid >= 4) brow += 896;     // second panel: +1024-128
    const char* gA = (const char*)A  + (((size_t)(m0 + wid*32 + ric) * K) << 1) + cb;
    const char* gB = (const char*)Bt + (((size_t)brow * K) << 1) + cb;
    size_t str8 = (size_t)K << 4;              // 8 rows stride in bytes
    int sRow = wid * 32 * 64;                  // stage dst base (elements)

    // fragment reads: logical col e -> phys e ^ ((row&7)*8); row&7 == fr&7
    int xorE = (lane & 7) << 3;
    int cbE0 = (q << 3) ^ xorE;                // k-step 0
    int cbE1 = cbE0 ^ 32;                      // k-step 1
    int aB0 = (wm * 128 + fr) * 64;
    int bB0 = (wn * 64  + fr) * 64;

    f32x4 acc[8][4] = {};
    int NT = K >> 6;

    #pragma unroll
    for (int i = 0; i < 4; i++){
        gload16(gA + (size_t)i * str8, &smem[0][0][sRow + i * 512]);
        gload16(gB + (size_t)i * str8, &smem[0][1][sRow + i * 512]);
    }

    for (int kt = 0; kt < NT; kt++){
        int cur = kt & 1, nxt = cur ^ 1;
        if (kt + 1 < NT){
            // issue next tile's 8 stages FIRST, then counted wait: tile kt's
            // 8 loads (issued one full tile ago) drain; these 8 keep flying.
            const char* pA = gA + (size_t)(kt + 1) * 128;
            const char* pB = gB + (size_t)(kt + 1) * 128;
            #pragma unroll
            for (int i = 0; i < 4; i++){
                gload16(pA + (size_t)i * str8, &smem[nxt][0][sRow + i * 512]);
                gload16(pB + (size_t)i * str8, &smem[nxt][1][sRow + i * 512]);
            }
            WVM8();
        } else {
            WVM0();
        }
        SBAR();   // tile kt staged for all waves

        const u16* sA = &smem[cur][0][0];
        const u16* sB = &smem[cur][1][0];
        short8 a0[4], a1[4], b0[4], b1[4];
        #pragma unroll
        for (int i = 0; i < 4; i++){
            a0[i] = *(const short8*)&sA[aB0 + i * 1024 + cbE0];
            a1[i] = *(const short8*)&sA[aB0 + i * 1024 + cbE1];
            b0[i] = *(const short8*)&sB[bB0 + i * 1024 + cbE0];
            b1[i] = *(const short8*)&sB[bB0 + i * 1024 + cbE1];
        }
        #pragma unroll
        for (int mi = 0; mi < 4; mi++)
            #pragma unroll
            for (int ni = 0; ni < 4; ni++){
                acc[mi][ni] = MF(a0[mi], b0[ni], acc[mi][ni]);
                acc[mi][ni] = MF(a1[mi], b1[ni], acc[mi][ni]);
            }
        short8 c0[4], c1[4];
        #pragma unroll
        for (int i = 0; i < 4; i++){
            c0[i] = *(const short8*)&sA[aB0 + (i + 4) * 1024 + cbE0];
            c1[i] = *(const short8*)&sA[aB0 + (i + 4) * 1024 + cbE1];
        }
        #pragma unroll
        for (int mi = 0; mi < 4; mi++)
            #pragma unroll
            for (int ni = 0; ni < 4; ni++){
                acc[mi + 4][ni] = MF(c0[mi], b0[ni], acc[mi + 4][ni]);
                acc[mi + 4][ni] = MF(c1[mi], b1[ni], acc[mi + 4][ni]);
            }
        SBAR();   // end of tile: slot nxt-of-next-iter (= cur) now reusable
    }

    int col = lane & 15, rb = q * 4;

    if constexpr (EPI == 3){
        // gating epilogue: waves wn>=2 hold fg columns; exchange via LDS.
        float* xch = (float*)&smem[0][0][0];   // f32[256][128], q-XOR swizzled
        if (wn >= 2){
            #pragma unroll
            for (int mi = 0; mi < 8; mi++){
                #pragma unroll
                for (int ni = 0; ni < 4; ni++){
                    int tc = (wn - 2) * 64 + ni * 16 + col;   // 0..127
                    float bv = bias[1024 + n0 + tc];
                    #pragma unroll
                    for (int r = 0; r < 4; r++){
                        int row = wm * 128 + mi * 16 + rb + r;
                        xch[row * 128 + (tc ^ (q << 4))] = sigm(acc[mi][ni][r] + bv);
                    }
                }
            }
        }
        WLG0();
        SBAR();
        if (wn < 2){
            #pragma unroll
            for (int mi = 0; mi < 8; mi++){
                #pragma unroll
                for (int ni = 0; ni < 4; ni++){
                    int tc = wn * 64 + ni * 16 + col;          // 0..127
                    int d  = n0 + tc;
                    float bv = bias[d];
                    #pragma unroll
                    for (int r = 0; r < 4; r++){
                        int row = wm * 128 + mi * 16 + rb + r;
                        int gm  = m0 + row;
                        float si = sigm(acc[mi][ni][r] + bv);
                        float sf = xch[row * 128 + (tc ^ (q << 4))];
                        of[(size_t)gm * Dn + d] =
                            si * xg[(size_t)gm * Dn + d] + sf * ag[(size_t)gm * Dn + d];
                    }
                }
            }
        }
        return;
    }

    #pragma unroll
    for (int mi = 0; mi < 8; mi++){
        #pragma unroll
        for (int ni = 0; ni < 4; ni++){
            int gn = n0 + wn * 64 + ni * 16 + col;
            float bv = bias[gn];
            #pragma unroll
            for (int r = 0; r < 4; r++){
                int gm = m0 + wm * 128 + mi * 16 + rb + r;
                float v = acc[mi][ni][r] + bv;
                if constexpr (EPI == 1){
                    ob[(size_t)gm * N + gn] = f2bf(fmaxf(v, 0.f));
                } else {
                    v += resid[(size_t)gm * N + gn];
                    of[(size_t)gm * N + gn] = v;
                    ob[(size_t)gm * 2 * N + N + gn] = f2bf(v);
                }
            }
        }
    }
}

// ---------------- launch -----------------------------------------------------
extern "C" void kernel_launch(void* const* d_in, const int* in_sizes, int n_in,
                              void* d_out, int out_size, void* d_ws, size_t ws_size,
                              hipStream_t stream)
{
    const float* x   = (const float*)d_in[0];
    const float* w1  = (const float*)d_in[1];
    const float* b1  = (const float*)d_in[2];
    const float* w2  = (const float*)d_in[3];
    const float* b2  = (const float*)d_in[4];
    const float* lng = (const float*)d_in[5];
    const float* lnb = (const float*)d_in[6];
    const float* wg  = (const float*)d_in[7];
    const float* bg  = (const float*)d_in[8];

    float* gated   = (float*)d_out;                    // [16384,1024]
    float* avg_out = (float*)d_out + NTOK * Dn;        // [16384,1024]

    char* ws = (char*)d_ws;
    u16*   w1t   = (u16*)  (ws + (0ull   << 20));      // 2 MB
    u16*   w2t   = (u16*)  (ws + (2ull   << 20));      // 2 MB
    u16*   wgt   = (u16*)  (ws + (4ull   << 20));      // 8 MB
    float* part  = (float*)(ws + (12ull  << 20));      // 0.5 MB
    float* avg   = (float*)(ws + (16ull  << 20));      // 64 MB
    u16*   ln    = (u16*)  (ws + (80ull  << 20));      // 32 MB
    u16*   inter = (u16*)  (ws + (112ull << 20));      // 32 MB
    u16*   cat   = (u16*)  (ws + (144ull << 20));      // 64 MB  -> total 208 MB

    // weights -> bf16 transposed [N,K]
    k_wcvt<<<dim3(32 * 32), 256, 0, stream>>>(w1, w1t, Dn, Dn);
    k_wcvt<<<dim3(32 * 32), 256, 0, stream>>>(w2, w2t, Dn, Dn);
    k_wcvt<<<dim3(64 * 64), 256, 0, stream>>>(wg, wgt, 2 * Dn, 2 * Dn);

    // cumulative average (+ fused x->cat bf16)
    k_psum <<<dim3(Bn * NC * 4), 256, 0, stream>>>(x, part);
    k_pscan<<<dim3(Bn * Dn / 256), 256, 0, stream>>>(part);
    k_avg  <<<dim3(Bn * NC * 4), 256, 0, stream>>>(x, part, avg, cat);

    // LN
    k_ln<<<dim3((int)NTOK), 256, 0, stream>>>(avg, lng, lnb, ln);

    // FFN GEMMs (256x256 tiles, 512 threads)
    k_gemm<1><<<dim3((int)(NTOK / 256) * (Dn / 256)), 512, 0, stream>>>(
        ln, w1t, b1, nullptr, inter, nullptr, nullptr, nullptr,
        (int)NTOK, Dn, Dn);
    k_gemm<2><<<dim3((int)(NTOK / 256) * (Dn / 256)), 512, 0, stream>>>(
        inter, w2t, b2, avg_out, cat, avg, nullptr, nullptr,
        (int)NTOK, Dn, Dn);

    // gating GEMM, fused sigmoid-combine epilogue (writes gated directly)
    k_gemm<3><<<dim3((int)(NTOK / 256) * 8), 512, 0, stream>>>(
        cat, wgt, bg, gated, nullptr, nullptr, x, avg_out,
        (int)NTOK, 2 * Dn, 2 * Dn);
}

// Round 4
// 338.468 us; speedup vs baseline: 1.4470x; 1.1130x over previous
//
#include <hip/hip_runtime.h>

typedef unsigned short u16;
typedef __attribute__((ext_vector_type(8))) short short8;
typedef __attribute__((ext_vector_type(8))) unsigned short ushort8;
typedef __attribute__((ext_vector_type(4))) float f32x4;
typedef __attribute__((ext_vector_type(4))) unsigned short u16x4;

#define DEV static __device__ __forceinline__

DEV u16 f2bf(float f){
    unsigned u = __float_as_uint(f);
    u += 0x7fffu + ((u >> 16) & 1u);   // round-to-nearest-even
    return (u16)(u >> 16);
}
DEV float bf2f(u16 h){ return __uint_as_float(((unsigned)h) << 16); }
DEV float sigm(float v){ return 1.f / (1.f + __expf(-v)); }

DEV f32x4 MF(short8 a, short8 b, f32x4 c){
    return __builtin_amdgcn_mfma_f32_16x16x32_bf16(a, b, c, 0, 0, 0);
}
DEV void gload16(const void* g, u16* l){
    __builtin_amdgcn_global_load_lds(
        (const __attribute__((address_space(1))) void*)g,
        (__attribute__((address_space(3))) void*)l, 16, 0, 0);
}
DEV void stage_half(const char* gp, size_t K2, u16* dst){
    gload16(gp, dst);
    gload16(gp + (K2 << 3), dst + 512);
}

#define SBAR()   asm volatile("s_barrier" ::: "memory")
#define WVM(n)   asm volatile("s_waitcnt vmcnt(" #n ")" ::: "memory")
#define WLG0()   asm volatile("s_waitcnt lgkmcnt(0)" ::: "memory")

constexpr int Bn = 8, Sn = 2048, Dn = 1024;
constexpr int CH = 128, NC = Sn / CH;          // 16 chunks along S
constexpr size_t NTOK = (size_t)Bn * Sn;       // 16384 rows

// ---------------- weight convert + transpose: w[K,N] f32 -> wt[N,K] bf16 ----
__global__ __launch_bounds__(256) void k_wcvt(const float* __restrict__ w,
                                              u16* __restrict__ wt,
                                              int Kd, int Nd)
{
    __shared__ float tile[32][33];
    int nbn = Nd / 32;
    int bk = blockIdx.x / nbn, bn = blockIdx.x % nbn;
    int lx = threadIdx.x & 31, ly = threadIdx.x >> 5;   // 32 x 8
    #pragma unroll
    for (int i = 0; i < 32; i += 8)
        tile[ly + i][lx] = w[(size_t)(bk * 32 + ly + i) * Nd + bn * 32 + lx];
    __syncthreads();
    #pragma unroll
    for (int i = 0; i < 32; i += 8)
        wt[(size_t)(bn * 32 + ly + i) * Kd + bk * 32 + lx] = f2bf(tile[lx][ly + i]);
}

// ---------------- cumulative average (3-phase chunked scan) -----------------
__global__ __launch_bounds__(256) void k_psum(const float* __restrict__ x,
                                              float* __restrict__ part)
{
    int bx = blockIdx.x;
    int dblk = bx & 3; bx >>= 2;
    int c = bx & (NC - 1), b = bx >> 4;
    int d = dblk * 256 + threadIdx.x;
    const float* px = x + ((size_t)b * Sn + (size_t)c * CH) * Dn + d;
    float s = 0.f;
    #pragma unroll 4
    for (int i = 0; i < CH; i++) s += px[(size_t)i * Dn];
    part[((size_t)b * NC + c) * Dn + d] = s;
}

__global__ __launch_bounds__(256) void k_pscan(float* part)
{
    int g = blockIdx.x * 256 + threadIdx.x;   // 8192 columns
    int b = g >> 10, d = g & 1023;
    float run = 0.f;
    #pragma unroll
    for (int c = 0; c < NC; c++){
        size_t idx = ((size_t)b * NC + c) * Dn + d;
        float v = part[idx]; part[idx] = run; run += v;
    }
}

// avg + fused x->cat[:,0:1024] bf16 write
__global__ __launch_bounds__(256) void k_avg(const float* __restrict__ x,
                                             const float* __restrict__ part,
                                             float* __restrict__ avg,
                                             u16* __restrict__ cat)
{
    int bx = blockIdx.x;
    int dblk = bx & 3; bx >>= 2;
    int c = bx & (NC - 1), b = bx >> 4;
    int d = dblk * 256 + threadIdx.x;
    const float* px = x   + ((size_t)b * Sn + (size_t)c * CH) * Dn + d;
    float*       pa = avg + ((size_t)b * Sn + (size_t)c * CH) * Dn + d;
    u16*         pc = cat + ((size_t)b * Sn + (size_t)c * CH) * 2048 + d;
    float run = part[((size_t)b * NC + c) * Dn + d];
    for (int i = 0; i < CH; i++){
        float v = px[(size_t)i * Dn];
        run += v;
        int s = c * CH + i;
        pa[(size_t)i * Dn] = run / (float)(s + 1);
        pc[(size_t)i * 2048] = f2bf(v);
    }
}

// ---------------- layernorm: avg f32 -> ln bf16 -----------------------------
__global__ __launch_bounds__(256) void k_ln(const float* __restrict__ avg,
                                            const float* __restrict__ g,
                                            const float* __restrict__ bta,
                                            u16* __restrict__ out)
{
    size_t row = blockIdx.x;
    int t = threadIdx.x;
    const float4* pr = (const float4*)(avg + row * Dn);
    float4 v = pr[t];
    float s = v.x + v.y + v.z + v.w;
    float q = v.x * v.x + v.y * v.y + v.z * v.z + v.w * v.w;
    #pragma unroll
    for (int o = 32; o > 0; o >>= 1){
        s += __shfl_down(s, o, 64);
        q += __shfl_down(q, o, 64);
    }
    __shared__ float rs[4], rq[4];
    __shared__ float smu, srstd;
    int wid = t >> 6, lane = t & 63;
    if (lane == 0){ rs[wid] = s; rq[wid] = q; }
    __syncthreads();
    if (t == 0){
        float S = rs[0] + rs[1] + rs[2] + rs[3];
        float Q = rq[0] + rq[1] + rq[2] + rq[3];
        float mu = S * (1.f / Dn);
        float var = Q * (1.f / Dn) - mu * mu;
        smu = mu; srstd = rsqrtf(var + 1e-6f);
    }
    __syncthreads();
    float mu = smu, rstd = srstd;
    int d0 = t * 4;
    float4 gg = ((const float4*)g)[t];
    float4 bb = ((const float4*)bta)[t];
    u16x4 o;
    o[0] = f2bf((v.x - mu) * rstd * gg.x + bb.x);
    o[1] = f2bf((v.y - mu) * rstd * gg.y + bb.y);
    o[2] = f2bf((v.z - mu) * rstd * gg.z + bb.z);
    o[3] = f2bf((v.w - mu) * rstd * gg.w + bb.w);
    *(u16x4*)(out + row * Dn + d0) = o;
}

// ---------------- 256x256x64 MFMA GEMM, 4-phase counted-vmcnt pipeline ------
// Halves: A rows [0,128)/[128,256); B rows(=out cols) [0,128)/[128,256).
// Wave (wm,wn): A rows wm*64 + qa*128, B cols wn*32 + qb*128.
// Phases: P0 (qa0,qb0) reads A0,B0; P1 (qa0,qb1) reads B1; P2 (qa1,qb1)
// reads A1; P3 (qa1,qb0). Stage order for next tile: A0@P0,B0@P1,B1@P2,A1@P3.
// vmcnt(4) at P0/P1/P2 tops drains exactly the half needed (ledger verified).
// EPI 1: ob = bf16(relu(v))                                  (inter)
// EPI 2: v += resid; of = v; ob[2N stride,+N] = bf16(v)      (avg_out + cat)
// EPI 3: paired-panel gating, all-wave bf16 LDS exchange + vectorized combine
template<int EPI>
__global__ __launch_bounds__(512, 2)
void k_gemm(const u16* __restrict__ A, const u16* __restrict__ Bt,
            const float* __restrict__ bias,
            float* __restrict__ of, u16* __restrict__ ob,
            const float* __restrict__ resid,
            const float* __restrict__ xg, const float* __restrict__ ag,
            int M, int N, int K)
{
    __shared__ u16 smem[2][2][2][8192];   // [buf][A|B][half][128r x 64c] 128 KB

    int nbn = (EPI == 3) ? 8 : (N >> 8);
    int nwg = (M >> 8) * nbn;
    int bid = blockIdx.x;
    int swz = (bid & 7) * (nwg >> 3) + (bid >> 3);
    int bm = swz / nbn, bn = swz - bm * nbn;
    int m0 = bm << 8;
    int n0 = (EPI == 3) ? (bn << 7) : (bn << 8);

    int tid  = threadIdx.x;
    int wid  = tid >> 6, lane = tid & 63;
    int wm   = wid >> 2, wn = wid & 3;
    int fr   = lane & 15, q = lane >> 4;

    // staging: per half-matrix (128 rows x 64 cols = 16 KB), wave w covers
    // rows w*16..+15 via 2 gload16 (8 rows = 1 KB each). Source pre-swizzled
    // (rule #21): LDS linear, global col byte = phys ^ ((row&7)<<4).
    int srow = (wid << 4) + (lane >> 3);
    int cb   = ((lane & 7) << 4) ^ (((lane >> 3) & 7) << 4);
    size_t K2 = (size_t)K * 2;
    int b1base = (EPI == 3) ? (1024 + n0) : (n0 + 128);
    const char* gA0 = (const char*)A  + (size_t)(m0 + srow) * K2 + cb;
    const char* gA1 = (const char*)A  + (size_t)(m0 + 128 + srow) * K2 + cb;
    const char* gB0 = (const char*)Bt + (size_t)(n0 + srow) * K2 + cb;
    const char* gB1 = (const char*)Bt + (size_t)(b1base + srow) * K2 + cb;
    int w16 = wid << 10;                        // LDS dst base (elems)

    // fragment reads: phys elem = logical ^ ((row&7)<<3); row&7 == lane&7
    int xorE = (lane & 7) << 3;
    int cbE0 = ((q << 3) ^ xorE);
    int cbE1 = cbE0 ^ 32;
    int aOff = (wm * 64 + fr) * 64;            // row-in-half * 64
    int bOff = (wn * 32 + fr) * 64;

    f32x4 acc[8][4] = {};
    int NT = K >> 6;

    // prologue: tile 0, issue order A0,B0,B1,A1 (vmcnt ledger depends on it)
    stage_half(gA0, K2, &smem[0][0][0][w16]);
    stage_half(gB0, K2, &smem[0][1][0][w16]);
    stage_half(gB1, K2, &smem[0][1][1][w16]);
    stage_half(gA1, K2, &smem[0][0][1][w16]);

    for (int kt = 0; kt < NT; kt++){
        int cur = kt & 1, nxt = cur ^ 1;
        bool pre = (kt + 1) < NT;
        size_t toff = (size_t)(kt + 1) * 128;
        const u16* cA = &smem[cur][0][0][0];
        const u16* cB = &smem[cur][1][0][0];

        short8 a0f[4][2], a1f[4][2], b0f[2][2], b1f[2][2];

        // ---- P0: needs A0,B0 of tile kt
        WVM(4); SBAR();
        #pragma unroll
        for (int mi = 0; mi < 4; mi++){
            a0f[mi][0] = *(const short8*)&cA[aOff + mi * 1024 + cbE0];
            a0f[mi][1] = *(const short8*)&cA[aOff + mi * 1024 + cbE1];
        }
        #pragma unroll
        for (int ni = 0; ni < 2; ni++){
            b0f[ni][0] = *(const short8*)&cB[bOff + ni * 1024 + cbE0];
            b0f[ni][1] = *(const short8*)&cB[bOff + ni * 1024 + cbE1];
        }
        if (pre) stage_half(gA0 + toff, K2, &smem[nxt][0][0][w16]);
        WLG0();
        __builtin_amdgcn_sched_barrier(0);
        __builtin_amdgcn_s_setprio(1);
        #pragma unroll
        for (int mi = 0; mi < 4; mi++)
            #pragma unroll
            for (int ni = 0; ni < 2; ni++){
                acc[mi][ni] = MF(a0f[mi][0], b0f[ni][0], acc[mi][ni]);
                acc[mi][ni] = MF(a0f[mi][1], b0f[ni][1], acc[mi][ni]);
            }
        __builtin_amdgcn_s_setprio(0);

        // ---- P1: needs B1 of tile kt
        if (pre){ WVM(4); } else { WVM(2); }
        SBAR();
        #pragma unroll
        for (int ni = 0; ni < 2; ni++){
            b1f[ni][0] = *(const short8*)&cB[8192 + bOff + ni * 1024 + cbE0];
            b1f[ni][1] = *(const short8*)&cB[8192 + bOff + ni * 1024 + cbE1];
        }
        if (pre) stage_half(gB0 + toff, K2, &smem[nxt][1][0][w16]);
        WLG0();
        __builtin_amdgcn_sched_barrier(0);
        __builtin_amdgcn_s_setprio(1);
        #pragma unroll
        for (int mi = 0; mi < 4; mi++)
            #pragma unroll
            for (int ni = 0; ni < 2; ni++){
                acc[mi][ni + 2] = MF(a0f[mi][0], b1f[ni][0], acc[mi][ni + 2]);
                acc[mi][ni + 2] = MF(a0f[mi][1], b1f[ni][1], acc[mi][ni + 2]);
            }
        __builtin_amdgcn_s_setprio(0);

        // ---- P2: needs A1 of tile kt
        if (pre){ WVM(4); } else { WVM(0); }
        SBAR();
        #pragma unroll
        for (int mi = 0; mi < 4; mi++){
            a1f[mi][0] = *(const short8*)&cA[8192 + aOff + mi * 1024 + cbE0];
            a1f[mi][1] = *(const short8*)&cA[8192 + aOff + mi * 1024 + cbE1];
        }
        if (pre) stage_half(gB1 + toff, K2, &smem[nxt][1][1][w16]);
        WLG0();
        __builtin_amdgcn_sched_barrier(0);
        __builtin_amdgcn_s_setprio(1);
        #pragma unroll
        for (int mi = 0; mi < 4; mi++)
            #pragma unroll
            for (int ni = 0; ni < 2; ni++){
                acc[mi + 4][ni + 2] = MF(a1f[mi][0], b1f[ni][0], acc[mi + 4][ni + 2]);
                acc[mi + 4][ni + 2] = MF(a1f[mi][1], b1f[ni][1], acc[mi + 4][ni + 2]);
            }
        __builtin_amdgcn_s_setprio(0);

        // ---- P3: reuses a1,b0 (no reads, no wait, no barrier)
        if (pre) stage_half(gA1 + toff, K2, &smem[nxt][0][1][w16]);
        __builtin_amdgcn_s_setprio(1);
        #pragma unroll
        for (int mi = 0; mi < 4; mi++)
            #pragma unroll
            for (int ni = 0; ni < 2; ni++){
                acc[mi + 4][ni] = MF(a1f[mi][0], b0f[ni][0], acc[mi + 4][ni]);
                acc[mi + 4][ni] = MF(a1f[mi][1], b0f[ni][1], acc[mi + 4][ni]);
            }
        __builtin_amdgcn_s_setprio(0);
    }

    int col = lane & 15, rb = q * 4;

    if constexpr (EPI == 3){
        // all-wave exchange: both gates sigmoid'ed to bf16 LDS, then all
        // 8 waves do a vectorized combine over 32 rows each.
        u16* s_in = &smem[0][0][0][0];        // [256][128] bf16, 64 KB
        u16* s_fg = s_in + 32768;             // 64 KB
        float bi[2], bf_[2];
        #pragma unroll
        for (int ni = 0; ni < 2; ni++){
            bi[ni]  = bias[n0 + wn * 32 + ni * 16 + col];
            bf_[ni] = bias[1024 + n0 + wn * 32 + ni * 16 + col];
        }
        SBAR();   // protect exchange region vs other waves' last-tile reads
        #pragma unroll
        for (int mi = 0; mi < 8; mi++){
            int lrow = ((mi & 4) << 5) + wm * 64 + ((mi & 3) << 4) + rb;
            #pragma unroll
            for (int ni = 0; ni < 2; ni++){
                int c  = wn * 32 + ni * 16 + col;
                int cp = c ^ (q << 4);
                #pragma unroll
                for (int r = 0; r < 4; r++){
                    int row = lrow + r;
                    s_in[row * 128 + cp] = f2bf(sigm(acc[mi][ni][r] + bi[ni]));
                    s_fg[row * 128 + cp] = f2bf(sigm(acc[mi][ni + 2][r] + bf_[ni]));
                }
            }
        }
        WLG0(); SBAR();
        int rbase = wid * 32;
        #pragma unroll
        for (int rg = 0; rg < 8; rg++){
            int b4  = rbase + rg * 4;
            int row = b4 + (lane >> 4);
            int sw  = ((b4 >> 2) & 3) << 4;
            int c0  = (lane & 15) * 8;
            int cp  = c0 ^ sw;
            ushort8 iv = *(const ushort8*)&s_in[row * 128 + cp];
            ushort8 fv = *(const ushort8*)&s_fg[row * 128 + cp];
            size_t gb = (size_t)(m0 + row) * Dn + n0 + c0;
            float4 x0 = *(const float4*)&xg[gb], x1 = *(const float4*)&xg[gb + 4];
            float4 a0 = *(const float4*)&ag[gb], a1 = *(const float4*)&ag[gb + 4];
            float4 o0, o1;
            o0.x = bf2f(iv[0]) * x0.x + bf2f(fv[0]) * a0.x;
            o0.y = bf2f(iv[1]) * x0.y + bf2f(fv[1]) * a0.y;
            o0.z = bf2f(iv[2]) * x0.z + bf2f(fv[2]) * a0.z;
            o0.w = bf2f(iv[3]) * x0.w + bf2f(fv[3]) * a0.w;
            o1.x = bf2f(iv[4]) * x1.x + bf2f(fv[4]) * a1.x;
            o1.y = bf2f(iv[5]) * x1.y + bf2f(fv[5]) * a1.y;
            o1.z = bf2f(iv[6]) * x1.z + bf2f(fv[6]) * a1.z;
            o1.w = bf2f(iv[7]) * x1.w + bf2f(fv[7]) * a1.w;
            *(float4*)&of[gb] = o0;
            *(float4*)&of[gb + 4] = o1;
        }
        return;
    }

    #pragma unroll
    for (int mi = 0; mi < 8; mi++){
        int lrow = m0 + ((mi & 4) << 5) + wm * 64 + ((mi & 3) << 4) + rb;
        #pragma unroll
        for (int ni = 0; ni < 4; ni++){
            int gn = n0 + ((ni & 2) << 6) + wn * 32 + ((ni & 1) << 4) + col;
            float bv = bias[gn];
            #pragma unroll
            for (int r = 0; r < 4; r++){
                int gm = lrow + r;
                float v = acc[mi][ni][r] + bv;
                if constexpr (EPI == 1){
                    ob[(size_t)gm * N + gn] = f2bf(fmaxf(v, 0.f));
                } else {
                    v += resid[(size_t)gm * N + gn];
                    of[(size_t)gm * N + gn] = v;
                    ob[(size_t)gm * 2 * N + N + gn] = f2bf(v);
                }
            }
        }
    }
}

// ---------------- launch -----------------------------------------------------
extern "C" void kernel_launch(void* const* d_in, const int* in_sizes, int n_in,
                              void* d_out, int out_size, void* d_ws, size_t ws_size,
                              hipStream_t stream)
{
    const float* x   = (const float*)d_in[0];
    const float* w1  = (const float*)d_in[1];
    const float* b1  = (const float*)d_in[2];
    const float* w2  = (const float*)d_in[3];
    const float* b2  = (const float*)d_in[4];
    const float* lng = (const float*)d_in[5];
    const float* lnb = (const float*)d_in[6];
    const float* wg  = (const float*)d_in[7];
    const float* bg  = (const float*)d_in[8];

    float* gated   = (float*)d_out;                    // [16384,1024]
    float* avg_out = (float*)d_out + NTOK * Dn;        // [16384,1024]

    char* ws = (char*)d_ws;
    u16*   w1t   = (u16*)  (ws + (0ull   << 20));      // 2 MB
    u16*   w2t   = (u16*)  (ws + (2ull   << 20));      // 2 MB
    u16*   wgt   = (u16*)  (ws + (4ull   << 20));      // 8 MB
    float* part  = (float*)(ws + (12ull  << 20));      // 0.5 MB
    float* avg   = (float*)(ws + (16ull  << 20));      // 64 MB
    u16*   ln    = (u16*)  (ws + (80ull  << 20));      // 32 MB
    u16*   inter = (u16*)  (ws + (112ull << 20));      // 32 MB
    u16*   cat   = (u16*)  (ws + (144ull << 20));      // 64 MB  -> total 208 MB

    // weights -> bf16 transposed [N,K]
    k_wcvt<<<dim3(32 * 32), 256, 0, stream>>>(w1, w1t, Dn, Dn);
    k_wcvt<<<dim3(32 * 32), 256, 0, stream>>>(w2, w2t, Dn, Dn);
    k_wcvt<<<dim3(64 * 64), 256, 0, stream>>>(wg, wgt, 2 * Dn, 2 * Dn);

    // cumulative average (+ fused x->cat bf16)
    k_psum <<<dim3(Bn * NC * 4), 256, 0, stream>>>(x, part);
    k_pscan<<<dim3(Bn * Dn / 256), 256, 0, stream>>>(part);
    k_avg  <<<dim3(Bn * NC * 4), 256, 0, stream>>>(x, part, avg, cat);

    // LN
    k_ln<<<dim3((int)NTOK), 256, 0, stream>>>(avg, lng, lnb, ln);

    // FFN GEMMs (256x256 tiles, 512 threads)
    k_gemm<1><<<dim3((int)(NTOK / 256) * (Dn / 256)), 512, 0, stream>>>(
        ln, w1t, b1, nullptr, inter, nullptr, nullptr, nullptr,
        (int)NTOK, Dn, Dn);
    k_gemm<2><<<dim3((int)(NTOK / 256) * (Dn / 256)), 512, 0, stream>>>(
        inter, w2t, b2, avg_out, cat, avg, nullptr, nullptr,
        (int)NTOK, Dn, Dn);

    // gating GEMM, fused sigmoid-combine epilogue (writes gated directly)
    k_gemm<3><<<dim3((int)(NTOK / 256) * 8), 512, 0, stream>>>(
        cat, wgt, bg, gated, nullptr, nullptr, x, avg_out,
        (int)NTOK, 2 * Dn, 2 * Dn);
}

// Round 5
// 302.297 us; speedup vs baseline: 1.6201x; 1.1197x over previous
//
#include <hip/hip_runtime.h>

typedef unsigned short u16;
typedef __attribute__((ext_vector_type(8))) short short8;
typedef __attribute__((ext_vector_type(8))) unsigned short ushort8;
typedef __attribute__((ext_vector_type(4))) float f32x4;
typedef __attribute__((ext_vector_type(4))) unsigned short u16x4;

#define DEV static __device__ __forceinline__

DEV u16 f2bf(float f){
    unsigned u = __float_as_uint(f);
    u += 0x7fffu + ((u >> 16) & 1u);   // round-to-nearest-even
    return (u16)(u >> 16);
}
DEV float bf2f(u16 h){ return __uint_as_float(((unsigned)h) << 16); }
DEV float sigm(float v){ return 1.f / (1.f + __expf(-v)); }

DEV f32x4 MF(short8 a, short8 b, f32x4 c){
    return __builtin_amdgcn_mfma_f32_16x16x32_bf16(a, b, c, 0, 0, 0);
}
DEV void gload16(const void* g, u16* l){
    __builtin_amdgcn_global_load_lds(
        (const __attribute__((address_space(1))) void*)g,
        (__attribute__((address_space(3))) void*)l, 16, 0, 0);
}
DEV void stage_half(const char* gp, size_t K2, u16* dst){
    gload16(gp, dst);
    gload16(gp + (K2 << 3), dst + 512);
}

#define SBAR()   asm volatile("s_barrier" ::: "memory")
#define WVM(n)   asm volatile("s_waitcnt vmcnt(" #n ")" ::: "memory")
#define WLG(n)   asm volatile("s_waitcnt lgkmcnt(" #n ")" ::: "memory")
#define SCB()    __builtin_amdgcn_sched_barrier(0)

constexpr int Bn = 8, Sn = 2048, Dn = 1024;
constexpr int CH = 128, NC = Sn / CH;          // 16 chunks along S
constexpr size_t NTOK = (size_t)Bn * Sn;       // 16384 rows

// ---------------- weight convert + transpose: w[K,N] f32 -> wt[N,K] bf16 ----
__global__ __launch_bounds__(256) void k_wcvt(const float* __restrict__ w,
                                              u16* __restrict__ wt,
                                              int Kd, int Nd)
{
    __shared__ float tile[32][33];
    int nbn = Nd / 32;
    int bk = blockIdx.x / nbn, bn = blockIdx.x % nbn;
    int lx = threadIdx.x & 31, ly = threadIdx.x >> 5;   // 32 x 8
    #pragma unroll
    for (int i = 0; i < 32; i += 8)
        tile[ly + i][lx] = w[(size_t)(bk * 32 + ly + i) * Nd + bn * 32 + lx];
    __syncthreads();
    #pragma unroll
    for (int i = 0; i < 32; i += 8)
        wt[(size_t)(bn * 32 + ly + i) * Kd + bk * 32 + lx] = f2bf(tile[lx][ly + i]);
}

// ---------------- cumulative average (3-phase chunked scan) -----------------
__global__ __launch_bounds__(256) void k_psum(const float* __restrict__ x,
                                              float* __restrict__ part)
{
    int bx = blockIdx.x;
    int dblk = bx & 3; bx >>= 2;
    int c = bx & (NC - 1), b = bx >> 4;
    int d = dblk * 256 + threadIdx.x;
    const float* px = x + ((size_t)b * Sn + (size_t)c * CH) * Dn + d;
    float s = 0.f;
    #pragma unroll 4
    for (int i = 0; i < CH; i++) s += px[(size_t)i * Dn];
    part[((size_t)b * NC + c) * Dn + d] = s;
}

__global__ __launch_bounds__(256) void k_pscan(float* part)
{
    int g = blockIdx.x * 256 + threadIdx.x;   // 8192 columns
    int b = g >> 10, d = g & 1023;
    float run = 0.f;
    #pragma unroll
    for (int c = 0; c < NC; c++){
        size_t idx = ((size_t)b * NC + c) * Dn + d;
        float v = part[idx]; part[idx] = run; run += v;
    }
}

// avg (bf16) + fused x->cat[:,0:1024] bf16 write
__global__ __launch_bounds__(256) void k_avg(const float* __restrict__ x,
                                             const float* __restrict__ part,
                                             u16* __restrict__ avg,
                                             u16* __restrict__ cat)
{
    int bx = blockIdx.x;
    int dblk = bx & 3; bx >>= 2;
    int c = bx & (NC - 1), b = bx >> 4;
    int d = dblk * 256 + threadIdx.x;
    const float* px = x   + ((size_t)b * Sn + (size_t)c * CH) * Dn + d;
    u16*         pa = avg + ((size_t)b * Sn + (size_t)c * CH) * Dn + d;
    u16*         pc = cat + ((size_t)b * Sn + (size_t)c * CH) * 2048 + d;
    float run = part[((size_t)b * NC + c) * Dn + d];
    for (int i = 0; i < CH; i++){
        float v = px[(size_t)i * Dn];
        run += v;
        int s = c * CH + i;
        pa[(size_t)i * Dn] = f2bf(run / (float)(s + 1));
        pc[(size_t)i * 2048] = f2bf(v);
    }
}

// ---------------- layernorm: avg bf16 -> ln bf16 ----------------------------
__global__ __launch_bounds__(256) void k_ln(const u16* __restrict__ avg,
                                            const float* __restrict__ g,
                                            const float* __restrict__ bta,
                                            u16* __restrict__ out)
{
    size_t row = blockIdx.x;
    int t = threadIdx.x;
    u16x4 hv = ((const u16x4*)(avg + row * Dn))[t];
    float4 v = { bf2f(hv[0]), bf2f(hv[1]), bf2f(hv[2]), bf2f(hv[3]) };
    float s = v.x + v.y + v.z + v.w;
    float q = v.x * v.x + v.y * v.y + v.z * v.z + v.w * v.w;
    #pragma unroll
    for (int o = 32; o > 0; o >>= 1){
        s += __shfl_down(s, o, 64);
        q += __shfl_down(q, o, 64);
    }
    __shared__ float rs[4], rq[4];
    __shared__ float smu, srstd;
    int wid = t >> 6, lane = t & 63;
    if (lane == 0){ rs[wid] = s; rq[wid] = q; }
    __syncthreads();
    if (t == 0){
        float S = rs[0] + rs[1] + rs[2] + rs[3];
        float Q = rq[0] + rq[1] + rq[2] + rq[3];
        float mu = S * (1.f / Dn);
        float var = Q * (1.f / Dn) - mu * mu;
        smu = mu; srstd = rsqrtf(var + 1e-6f);
    }
    __syncthreads();
    float mu = smu, rstd = srstd;
    int d0 = t * 4;
    float4 gg = ((const float4*)g)[t];
    float4 bb = ((const float4*)bta)[t];
    u16x4 o;
    o[0] = f2bf((v.x - mu) * rstd * gg.x + bb.x);
    o[1] = f2bf((v.y - mu) * rstd * gg.y + bb.y);
    o[2] = f2bf((v.z - mu) * rstd * gg.z + bb.z);
    o[3] = f2bf((v.w - mu) * rstd * gg.w + bb.w);
    *(u16x4*)(out + row * Dn + d0) = o;
}

// ---------------- 256x256x64 MFMA GEMM, deep counted-vmcnt/lgkmcnt pipeline -
// C = A[M,K] x Bt[N,K]^T + bias
// Quadrants: P0 acc[0:4][0:2] (a0,b0); P1 acc[0:4][2:4] (a0,b1);
//            P2 acc[4:8][2:4] (a1,b1); P3 acc[4:8][0:2] (a1,b0).
// Reads: b0,b1 @P0 (lgkm 4); a1 @P1 (lgkm 8, runs under MFMA P1);
//        a0(t+1) @P3 (lgkm 8, runs under MFMA P3).
// Stage: A1(t+1)@P0, A0(t+2)@P1, B0(t+2)@P2, B1(t+2)@P3 (1 half/phase).
// vmcnt ledger (steady): P0=8, P1=8, P3=10. Tails peeled with exact waits.
// EPI 1: ob = bf16(relu(v))                                  (inter)
// EPI 2: v += bf2f(resid); of = v; ob[2N,+N] = bf16(v)       (avg_out + cat)
// EPI 3: paired-panel gating, all-wave bf16 LDS exchange; x/avg_out from cat
template<int EPI>
__global__ __launch_bounds__(512, 2)
void k_gemm(const u16* __restrict__ A, const u16* __restrict__ Bt,
            const float* __restrict__ bias,
            float* __restrict__ of, u16* __restrict__ ob,
            const u16* __restrict__ resid,
            int M, int N, int K)
{
    __shared__ u16 smem[2][2][2][8192];   // [buf][A|B][half][128r x 64c] 128 KB

    int nbn = (EPI == 3) ? 8 : (N >> 8);
    int nwg = (M >> 8) * nbn;
    int bid = blockIdx.x;
    int swz = (bid & 7) * (nwg >> 3) + (bid >> 3);
    int bm = swz / nbn, bn = swz - bm * nbn;
    int m0 = bm << 8;
    int n0 = (EPI == 3) ? (bn << 7) : (bn << 8);

    int tid  = threadIdx.x;
    int wid  = tid >> 6, lane = tid & 63;
    int wm   = wid >> 2, wn = wid & 3;
    int fr   = lane & 15, q = lane >> 4;

    // staging addresses (source pre-swizzled per rule #21; LDS linear)
    int srow = (wid << 4) + (lane >> 3);
    int cb   = ((lane & 7) << 4) ^ (((lane >> 3) & 7) << 4);
    size_t K2 = (size_t)K * 2;
    int b1base = (EPI == 3) ? (1024 + n0) : (n0 + 128);
    const char* gA0 = (const char*)A  + (size_t)(m0 + srow) * K2 + cb;
    const char* gA1 = (const char*)A  + (size_t)(m0 + 128 + srow) * K2 + cb;
    const char* gB0 = (const char*)Bt + (size_t)(n0 + srow) * K2 + cb;
    const char* gB1 = (const char*)Bt + (size_t)(b1base + srow) * K2 + cb;
    int w16 = wid << 10;

    // fragment reads: phys elem = logical ^ ((row&7)<<3); row&7 == lane&7
    int xorE = (lane & 7) << 3;
    int cbE0 = ((q << 3) ^ xorE);
    int cbE1 = cbE0 ^ 32;
    int aOff = (wm * 64 + fr) * 64;
    int bOff = (wn * 32 + fr) * 64;

    f32x4 acc[8][4] = {};
    short8 a0f[4][2], a1f[4][2], b0f[2][2], b1f[2][2];
    int NT = K >> 6;

#define ST_A0(t) stage_half(gA0 + (size_t)(t) * 128, K2, &smem[(t)&1][0][0][w16])
#define ST_A1(t) stage_half(gA1 + (size_t)(t) * 128, K2, &smem[(t)&1][0][1][w16])
#define ST_B0(t) stage_half(gB0 + (size_t)(t) * 128, K2, &smem[(t)&1][1][0][w16])
#define ST_B1(t) stage_half(gB1 + (size_t)(t) * 128, K2, &smem[(t)&1][1][1][w16])
#define RD_A(Fr, t, half) { const u16* _p = &smem[(t)&1][0][half][0];           \
    _Pragma("unroll") for (int i = 0; i < 4; i++){                              \
        Fr[i][0] = *(const short8*)&_p[aOff + i * 1024 + cbE0];                 \
        Fr[i][1] = *(const short8*)&_p[aOff + i * 1024 + cbE1]; } }
#define RD_B(Fr, t, half) { const u16* _p = &smem[(t)&1][1][half][0];           \
    _Pragma("unroll") for (int i = 0; i < 2; i++){                              \
        Fr[i][0] = *(const short8*)&_p[bOff + i * 1024 + cbE0];                 \
        Fr[i][1] = *(const short8*)&_p[bOff + i * 1024 + cbE1]; } }
#define MMQ(Af, Bf, mo, no)                                                     \
    __builtin_amdgcn_s_setprio(1);                                              \
    _Pragma("unroll") for (int mi = 0; mi < 4; mi++)                            \
        _Pragma("unroll") for (int ni = 0; ni < 2; ni++){                       \
            acc[mi+(mo)][ni+(no)] = MF(Af[mi][0], Bf[ni][0], acc[mi+(mo)][ni+(no)]); \
            acc[mi+(mo)][ni+(no)] = MF(Af[mi][1], Bf[ni][1], acc[mi+(mo)][ni+(no)]); \
        }                                                                        \
    __builtin_amdgcn_s_setprio(0);

    // prologue: issue order fixes the vmcnt ledger
    ST_A0(0); ST_B0(0); ST_B1(0); ST_A1(0); ST_A0(1); ST_B0(1); ST_B1(1);
    WVM(12); SBAR();
    RD_A(a0f, 0, 0);

    for (int t = 0; t + 2 < NT; ++t){
        // P0
        WVM(8); SBAR();
        ST_A1(t + 1);
        RD_B(b0f, t, 0); SCB();
        RD_B(b1f, t, 1);
        WLG(4); SCB();
        MMQ(a0f, b0f, 0, 0);
        // P1
        WVM(8); SBAR();
        ST_A0(t + 2);
        RD_A(a1f, t, 1);
        WLG(8); SCB();
        MMQ(a0f, b1f, 0, 2);
        // P2
        SBAR();
        ST_B0(t + 2);
        WLG(0); SCB();
        MMQ(a1f, b1f, 4, 2);
        // P3
        WVM(10); SBAR();
        ST_B1(t + 2);
        RD_A(a0f, t + 1, 0);
        WLG(8); SCB();
        MMQ(a1f, b0f, 4, 0);
    }
    {   // t = NT-2 (stages for tile NT skipped; exact tail waits)
        int t = NT - 2;
        WVM(8); SBAR();
        ST_A1(t + 1);
        RD_B(b0f, t, 0); SCB();
        RD_B(b1f, t, 1);
        WLG(4); SCB();
        MMQ(a0f, b0f, 0, 0);
        WVM(8); SBAR();
        RD_A(a1f, t, 1);
        WLG(8); SCB();
        MMQ(a0f, b1f, 0, 2);
        SBAR();
        WLG(0); SCB();
        MMQ(a1f, b1f, 4, 2);
        WVM(6); SBAR();
        RD_A(a0f, t + 1, 0);
        WLG(8); SCB();
        MMQ(a1f, b0f, 4, 0);
    }
    {   // t = NT-1 (last)
        int t = NT - 1;
        WVM(2); SBAR();
        RD_B(b0f, t, 0); SCB();
        RD_B(b1f, t, 1);
        WLG(4); SCB();
        MMQ(a0f, b0f, 0, 0);
        WVM(0); SBAR();
        RD_A(a1f, t, 1);
        WLG(8); SCB();
        MMQ(a0f, b1f, 0, 2);
        SBAR();
        WLG(0); SCB();
        MMQ(a1f, b1f, 4, 2);
        MMQ(a1f, b0f, 4, 0);
    }

    int col = lane & 15, rb = q * 4;

    if constexpr (EPI == 3){
        u16* s_in = &smem[0][0][0][0];        // [256][128] bf16, 64 KB
        u16* s_fg = s_in + 32768;             // 64 KB
        float bi[2], bf_[2];
        #pragma unroll
        for (int ni = 0; ni < 2; ni++){
            bi[ni]  = bias[n0 + wn * 32 + ni * 16 + col];
            bf_[ni] = bias[1024 + n0 + wn * 32 + ni * 16 + col];
        }
        SBAR();   // all waves done reading K-tile LDS
        #pragma unroll
        for (int mi = 0; mi < 8; mi++){
            int lrow = ((mi & 4) << 5) + wm * 64 + ((mi & 3) << 4) + rb;
            #pragma unroll
            for (int ni = 0; ni < 2; ni++){
                int c  = wn * 32 + ni * 16 + col;
                int cp = c ^ (q << 4);
                #pragma unroll
                for (int r = 0; r < 4; r++){
                    int row = lrow + r;
                    s_in[row * 128 + cp] = f2bf(sigm(acc[mi][ni][r] + bi[ni]));
                    s_fg[row * 128 + cp] = f2bf(sigm(acc[mi][ni + 2][r] + bf_[ni]));
                }
            }
        }
        WLG(0); SBAR();
        int rbase = wid * 32;
        #pragma unroll
        for (int rg = 0; rg < 8; rg++){
            int b4  = rbase + rg * 4;
            int row = b4 + (lane >> 4);
            int sw  = ((b4 >> 2) & 3) << 4;
            int c0  = (lane & 15) * 8;
            int cp  = c0 ^ sw;
            ushort8 iv = *(const ushort8*)&s_in[row * 128 + cp];
            ushort8 fv = *(const ushort8*)&s_fg[row * 128 + cp];
            size_t ga = (size_t)(m0 + row) * 2048 + n0 + c0;   // cat row base
            ushort8 xv = *(const ushort8*)&A[ga];
            ushort8 av = *(const ushort8*)&A[ga + 1024];
            size_t gb = (size_t)(m0 + row) * Dn + n0 + c0;
            float4 o0, o1;
            o0.x = bf2f(iv[0]) * bf2f(xv[0]) + bf2f(fv[0]) * bf2f(av[0]);
            o0.y = bf2f(iv[1]) * bf2f(xv[1]) + bf2f(fv[1]) * bf2f(av[1]);
            o0.z = bf2f(iv[2]) * bf2f(xv[2]) + bf2f(fv[2]) * bf2f(av[2]);
            o0.w = bf2f(iv[3]) * bf2f(xv[3]) + bf2f(fv[3]) * bf2f(av[3]);
            o1.x = bf2f(iv[4]) * bf2f(xv[4]) + bf2f(fv[4]) * bf2f(av[4]);
            o1.y = bf2f(iv[5]) * bf2f(xv[5]) + bf2f(fv[5]) * bf2f(av[5]);
            o1.z = bf2f(iv[6]) * bf2f(xv[6]) + bf2f(fv[6]) * bf2f(av[6]);
            o1.w = bf2f(iv[7]) * bf2f(xv[7]) + bf2f(fv[7]) * bf2f(av[7]);
            *(float4*)&of[gb] = o0;
            *(float4*)&of[gb + 4] = o1;
        }
        return;
    }

    #pragma unroll
    for (int mi = 0; mi < 8; mi++){
        int lrow = m0 + ((mi & 4) << 5) + wm * 64 + ((mi & 3) << 4) + rb;
        #pragma unroll
        for (int ni = 0; ni < 4; ni++){
            int gn = n0 + ((ni & 2) << 6) + wn * 32 + ((ni & 1) << 4) + col;
            float bv = bias[gn];
            #pragma unroll
            for (int r = 0; r < 4; r++){
                int gm = lrow + r;
                float v = acc[mi][ni][r] + bv;
                if constexpr (EPI == 1){
                    ob[(size_t)gm * N + gn] = f2bf(fmaxf(v, 0.f));
                } else {
                    v += bf2f(resid[(size_t)gm * N + gn]);
                    of[(size_t)gm * N + gn] = v;
                    ob[(size_t)gm * 2 * N + N + gn] = f2bf(v);
                }
            }
        }
    }
}

// ---------------- launch -----------------------------------------------------
extern "C" void kernel_launch(void* const* d_in, const int* in_sizes, int n_in,
                              void* d_out, int out_size, void* d_ws, size_t ws_size,
                              hipStream_t stream)
{
    const float* x   = (const float*)d_in[0];
    const float* w1  = (const float*)d_in[1];
    const float* b1  = (const float*)d_in[2];
    const float* w2  = (const float*)d_in[3];
    const float* b2  = (const float*)d_in[4];
    const float* lng = (const float*)d_in[5];
    const float* lnb = (const float*)d_in[6];
    const float* wg  = (const float*)d_in[7];
    const float* bg  = (const float*)d_in[8];

    float* gated   = (float*)d_out;                    // [16384,1024]
    float* avg_out = (float*)d_out + NTOK * Dn;        // [16384,1024]

    char* ws = (char*)d_ws;
    u16*   w1t   = (u16*)  (ws + (0ull   << 20));      // 2 MB
    u16*   w2t   = (u16*)  (ws + (2ull   << 20));      // 2 MB
    u16*   wgt   = (u16*)  (ws + (4ull   << 20));      // 8 MB
    float* part  = (float*)(ws + (12ull  << 20));      // 0.5 MB
    u16*   avg   = (u16*)  (ws + (16ull  << 20));      // 32 MB (bf16)
    u16*   ln    = (u16*)  (ws + (80ull  << 20));      // 32 MB
    u16*   inter = (u16*)  (ws + (112ull << 20));      // 32 MB
    u16*   cat   = (u16*)  (ws + (144ull << 20));      // 64 MB  -> total 208 MB

    // weights -> bf16 transposed [N,K]
    k_wcvt<<<dim3(32 * 32), 256, 0, stream>>>(w1, w1t, Dn, Dn);
    k_wcvt<<<dim3(32 * 32), 256, 0, stream>>>(w2, w2t, Dn, Dn);
    k_wcvt<<<dim3(64 * 64), 256, 0, stream>>>(wg, wgt, 2 * Dn, 2 * Dn);

    // cumulative average (+ fused x->cat bf16)
    k_psum <<<dim3(Bn * NC * 4), 256, 0, stream>>>(x, part);
    k_pscan<<<dim3(Bn * Dn / 256), 256, 0, stream>>>(part);
    k_avg  <<<dim3(Bn * NC * 4), 256, 0, stream>>>(x, part, avg, cat);

    // LN
    k_ln<<<dim3((int)NTOK), 256, 0, stream>>>(avg, lng, lnb, ln);

    // FFN GEMMs (256x256 tiles, 512 threads)
    k_gemm<1><<<dim3((int)(NTOK / 256) * (Dn / 256)), 512, 0, stream>>>(
        ln, w1t, b1, nullptr, inter, nullptr, (int)NTOK, Dn, Dn);
    k_gemm<2><<<dim3((int)(NTOK / 256) * (Dn / 256)), 512, 0, stream>>>(
        inter, w2t, b2, avg_out, cat, avg, (int)NTOK, Dn, Dn);

    // gating GEMM, fused sigmoid-combine epilogue (writes gated directly)
    k_gemm<3><<<dim3((int)(NTOK / 256) * 8), 512, 0, stream>>>(
        cat, wgt, bg, gated, nullptr, nullptr, (int)NTOK, 2 * Dn, 2 * Dn);
}